// Round 2
// baseline (4444.194 us; speedup 1.0000x reference)
//
#include <hip/hip_runtime.h>
#include <hip/hip_bf16.h>
#include <math.h>

#define D    256
#define BT   64     // tile timesteps = chunk length
#define BN   64     // tile channels
#define BK   32     // k-slice
#define CT   64     // scan chunk length (== BT)
#define NSEG 16     // segments per chunk (CT/4)

typedef unsigned short u16;

__device__ __forceinline__ float b2f(u16 v) {
    union { unsigned int u; float f; } x; x.u = ((unsigned int)v) << 16; return x.f;
}
__device__ __forceinline__ u16 f2b(float f) {
    union { unsigned int u; float f; } x; x.f = f;
    unsigned int lsb = (x.u >> 16) & 1;
    x.u += 0x7fffu + lsb;          // round-to-nearest-even
    return (u16)(x.u >> 16);
}

// ---------------------------------------------------------------------------
// q_init: q[t][d] = bf16(question[d])
// ---------------------------------------------------------------------------
__global__ __launch_bounds__(256) void q_init_kernel(
    u16* __restrict__ q, const float* __restrict__ question, long total4)
{
    long i = (long)blockIdx.x * 256 + threadIdx.x;   // one per 4 elements
    if (i < total4) {
        int col = (int)(i & (D/4 - 1)) * 4;
        ushort4 v;
        v.x = f2b(question[col + 0]);
        v.y = f2b(question[col + 1]);
        v.z = f2b(question[col + 2]);
        v.w = f2b(question[col + 3]);
        *(ushort4*)(q + i * 4) = v;
    }
}

// ---------------------------------------------------------------------------
// Fused gates-GEMM + chunk scan.
//   PHASE 0 (p1): compute per-chunk affine aggregate (A,B) -> aggA/aggB
//   PHASE 1 (p3): recompute gates, replay chunk from hinit[c], write h:
//                 FWD: hout[t][n]  = bf16(h_f)
//                 BWD: hout[t][n] += h_b   (bf16 read-modify-write)
// One block = one (chunk, 64-channel slice): 64x64 output tile, 3 GEMM
// streams (xq@Wz, x@Whx, q@Whq), k=256 staged in BK=32 slices.
// ---------------------------------------------------------------------------
template<int FWD, int PHASE>
__global__ __launch_bounds__(256) void qrn_gemm_kernel(
    const float* __restrict__ x, const u16* __restrict__ q,
    const float* __restrict__ Wz, const float* __restrict__ bz,
    const float* __restrict__ Whx, const float* __restrict__ Whq,
    const float* __restrict__ bh,
    float* __restrict__ aggA, float* __restrict__ aggB,
    const float* __restrict__ hinit, u16* __restrict__ hout)
{
    __shared__ float s_x [BK][BT];
    __shared__ float s_q [BK][BT];
    __shared__ float s_xq[BK][BT];
    __shared__ float s_wz[BK][BN];
    __shared__ float s_wx[BK][BN];
    __shared__ float s_wq[BK][BN];
    __shared__ float s_segA[NSEG][BN];
    __shared__ float s_segB[NSEG][BN];
    __shared__ float s_h[NSEG][BN];

    const int c   = (int)(blockIdx.x >> 2);       // chunk id
    const int t0  = c * BT;
    const int n0  = (int)(blockIdx.x & 3) * BN;
    const int tid = threadIdx.x;
    const int tx  = tid & 15;                     // channel microtile
    const int ty  = tid >> 4;                     // time microtile (segment id)

    float accz[4][4] = {{0.f}};
    float acch[4][4] = {{0.f}};

    for (int k0 = 0; k0 < D; k0 += BK) {
        #pragma unroll
        for (int s = 0; s < 2; ++s) {
            int idx = tid * 2 + s;               // 0..511
            int r   = idx >> 3;                  // t row 0..63
            int cc  = (idx & 7) * 4;             // k col 0..28
            float4  xv = *(const float4*)(x + (size_t)(t0 + r) * D + k0 + cc);
            ushort4 qv = *(const ushort4*)(q + (size_t)(t0 + r) * D + k0 + cc);
            float q0 = b2f(qv.x), q1 = b2f(qv.y), q2 = b2f(qv.z), q3 = b2f(qv.w);
            s_x [cc+0][r] = xv.x; s_x [cc+1][r] = xv.y; s_x [cc+2][r] = xv.z; s_x [cc+3][r] = xv.w;
            s_q [cc+0][r] = q0;   s_q [cc+1][r] = q1;   s_q [cc+2][r] = q2;   s_q [cc+3][r] = q3;
            s_xq[cc+0][r] = xv.x*q0; s_xq[cc+1][r] = xv.y*q1;
            s_xq[cc+2][r] = xv.z*q2; s_xq[cc+3][r] = xv.w*q3;
        }
        #pragma unroll
        for (int s = 0; s < 2; ++s) {
            int idx = tid * 2 + s;               // 0..511
            int r   = idx >> 4;                  // k row 0..31
            int cc  = (idx & 15) * 4;            // n col 0..60
            *(float4*)(&s_wz[r][cc]) = *(const float4*)(Wz  + (size_t)(k0 + r) * D + n0 + cc);
            *(float4*)(&s_wx[r][cc]) = *(const float4*)(Whx + (size_t)(k0 + r) * D + n0 + cc);
            *(float4*)(&s_wq[r][cc]) = *(const float4*)(Whq + (size_t)(k0 + r) * D + n0 + cc);
        }
        __syncthreads();

        #pragma unroll 8
        for (int k = 0; k < BK; ++k) {
            float4 vx4 = *(const float4*)(&s_x [k][ty*4]);
            float4 vq4 = *(const float4*)(&s_q [k][ty*4]);
            float4 vz4 = *(const float4*)(&s_xq[k][ty*4]);
            float4 wz4 = *(const float4*)(&s_wz[k][tx*4]);
            float4 wx4 = *(const float4*)(&s_wx[k][tx*4]);
            float4 wq4 = *(const float4*)(&s_wq[k][tx*4]);
            const float vx[4] = {vx4.x, vx4.y, vx4.z, vx4.w};
            const float vq[4] = {vq4.x, vq4.y, vq4.z, vq4.w};
            const float vz[4] = {vz4.x, vz4.y, vz4.z, vz4.w};
            const float wz[4] = {wz4.x, wz4.y, wz4.z, wz4.w};
            const float wx[4] = {wx4.x, wx4.y, wx4.z, wx4.w};
            const float wq[4] = {wq4.x, wq4.y, wq4.z, wq4.w};
            #pragma unroll
            for (int i = 0; i < 4; ++i)
                #pragma unroll
                for (int j = 0; j < 4; ++j) {
                    accz[i][j] = fmaf(vz[i], wz[j], accz[i][j]);
                    acch[i][j] = fmaf(vx[i], wx[j], acch[i][j]);
                    acch[i][j] = fmaf(vq[i], wq[j], acch[i][j]);
                }
        }
        __syncthreads();
    }

    // gate epilogue: a = 1-z, b = z*tanh(gh)
    float av[4][4], bv[4][4];
    #pragma unroll
    for (int i = 0; i < 4; ++i)
        #pragma unroll
        for (int j = 0; j < 4; ++j) {
            int n = n0 + tx*4 + j;
            float gz = accz[i][j] + bz[n];
            float gh = acch[i][j] + bh[n];
            float z  = 1.0f / (1.0f + __expf(-gz));
            av[i][j] = 1.0f - z;
            bv[i][j] = z * tanhf(gh);
        }

    // per-thread 4-step segment aggregate, per channel column
    #pragma unroll
    for (int j = 0; j < 4; ++j) {
        float A = 1.f, B = 0.f;
        if (FWD) {
            #pragma unroll
            for (int i = 0; i < 4; ++i) { A = av[i][j] * A; B = fmaf(av[i][j], B, bv[i][j]); }
        } else {
            #pragma unroll
            for (int i = 3; i >= 0; --i) { A = av[i][j] * A; B = fmaf(av[i][j], B, bv[i][j]); }
        }
        s_segA[ty][tx*4 + j] = A;
        s_segB[ty][tx*4 + j] = B;
    }
    __syncthreads();

    if (PHASE == 0) {
        // compose 16 segments -> chunk aggregate
        if (tid < BN) {
            int n = tid;
            float A = 1.f, B = 0.f;
            if (FWD) {
                #pragma unroll
                for (int sg = 0; sg < NSEG; ++sg) {
                    float a = s_segA[sg][n];
                    A = a * A; B = fmaf(a, B, s_segB[sg][n]);
                }
            } else {
                #pragma unroll
                for (int sg = NSEG - 1; sg >= 0; --sg) {
                    float a = s_segA[sg][n];
                    A = a * A; B = fmaf(a, B, s_segB[sg][n]);
                }
            }
            aggA[(size_t)c * D + n0 + n] = A;
            aggB[(size_t)c * D + n0 + n] = B;
        }
    } else {
        // segment-start states from hinit
        if (tid < BN) {
            int n = tid;
            float h = hinit[(size_t)c * D + n0 + n];
            if (FWD) {
                #pragma unroll
                for (int sg = 0; sg < NSEG; ++sg) {
                    s_h[sg][n] = h;
                    h = fmaf(s_segA[sg][n], h, s_segB[sg][n]);
                }
            } else {
                #pragma unroll
                for (int sg = NSEG - 1; sg >= 0; --sg) {
                    s_h[sg][n] = h;
                    h = fmaf(s_segA[sg][n], h, s_segB[sg][n]);
                }
            }
        }
        __syncthreads();
        // replay 4 steps, write h (fwd) or accumulate (bwd)
        #pragma unroll
        for (int j = 0; j < 4; ++j) {
            int n = tx*4 + j;
            float h = s_h[ty][n];
            if (FWD) {
                #pragma unroll
                for (int i = 0; i < 4; ++i) {
                    h = fmaf(av[i][j], h, bv[i][j]);
                    size_t o = (size_t)(t0 + ty*4 + i) * D + n0 + n;
                    hout[o] = f2b(h);
                }
            } else {
                #pragma unroll
                for (int i = 3; i >= 0; --i) {
                    h = fmaf(av[i][j], h, bv[i][j]);
                    size_t o = (size_t)(t0 + ty*4 + i) * D + n0 + n;
                    hout[o] = f2b(b2f(hout[o]) + h);
                }
            }
        }
    }
}

// ---------------------------------------------------------------------------
// inter-chunk scan: one block per channel, Hillis-Steele over 1024 chunk
// aggregates in processing order. Writes per-chunk incoming state hinit;
// optionally final state (== h[last processed t]) to out_final.
// ---------------------------------------------------------------------------
__global__ __launch_bounds__(256) void scan_p2_kernel(
    const float* __restrict__ aggA, const float* __restrict__ aggB,
    float* __restrict__ hinit, float* __restrict__ out_final, int fwd, int nch)
{
    __shared__ float sA[256], sB[256];
    const int n = blockIdx.x, tid = threadIdx.x;
    const int per = nch >> 8;               // 4
    float lA[8], lB[8];
    float A = 1.f, B = 0.f;
    for (int j = 0; j < per; ++j) {
        int p = tid * per + j;
        int c = fwd ? p : (nch - 1 - p);
        float a = aggA[(size_t)c * D + n];
        float b = aggB[(size_t)c * D + n];
        lA[j] = a; lB[j] = b;
        A = a * A;
        B = fmaf(a, B, b);
    }
    sA[tid] = A; sB[tid] = B;
    __syncthreads();
    for (int off = 1; off < 256; off <<= 1) {
        float pA = 1.f, pB = 0.f;
        if (tid >= off) { pA = sA[tid - off]; pB = sB[tid - off]; }
        __syncthreads();
        if (tid >= off) {
            float cA = sA[tid], cB = sB[tid];
            sA[tid] = pA * cA;
            sB[tid] = fmaf(cA, pB, cB);
        }
        __syncthreads();
    }
    float eB = (tid > 0) ? sB[tid - 1] : 0.f;
    for (int j = 0; j < per; ++j) {
        int p = tid * per + j;
        int c = fwd ? p : (nch - 1 - p);
        hinit[(size_t)c * D + n] = eB;
        eB = fmaf(lA[j], eB, lB[j]);
    }
    if (out_final != nullptr && tid == 0) out_final[n] = sB[255];
}

// ---------------------------------------------------------------------------
extern "C" void kernel_launch(void* const* d_in, const int* in_sizes, int n_in,
                              void* d_out, int out_size, void* d_ws, size_t ws_size,
                              hipStream_t stream) {
    const float* story    = (const float*)d_in[0];
    const float* question = (const float*)d_in[1];
    const float* Wz_f = (const float*)d_in[2];
    const float* bz_f = (const float*)d_in[3];
    const float* Wh_f = (const float*)d_in[4];
    const float* bh_f = (const float*)d_in[5];
    const float* Wz_b = (const float*)d_in[6];
    const float* bz_b = (const float*)d_in[7];
    const float* Wh_b = (const float*)d_in[8];
    const float* bh_b = (const float*)d_in[9];

    const int T    = in_sizes[0] / D;        // 65536
    const int NCH  = T / CT;                 // 1024
    const size_t TD = (size_t)T * D;

    // workspace: 2x bf16 [T,D] ping-pong q + fp32 aggregates  (~67 MB)
    u16*   qA   = (u16*)d_ws;
    u16*   qB   = qA + TD;
    float* aggA = (float*)(qB + TD);
    float* aggB = aggA + (size_t)NCH * D;
    float* hini = aggB + (size_t)NCH * D;

    // layer-0 q = broadcast(question)
    {
        long total4 = (long)(TD / 4);
        q_init_kernel<<<dim3((unsigned)(total4 / 256)), dim3(256), 0, stream>>>(
            qA, question, total4);
    }

    const u16* qcur  = qA;
    u16*       qnext = qB;
    dim3 gGrid((T / BT) * (D / BN));         // 4096

    for (int l = 0; l < 3; ++l) {
        const float* Wz  = Wz_f + (size_t)l * D * D;
        const float* bz  = bz_f + (size_t)l * D;
        const float* Whx = Wh_f + (size_t)l * 2 * D * D;
        const float* Whq = Whx + (size_t)D * D;
        const float* bh  = bh_f + (size_t)l * D;

        if (l == 2) {
            // only h_fwd[T-1] needed
            qrn_gemm_kernel<1,0><<<gGrid, 256, 0, stream>>>(
                story, qcur, Wz, bz, Whx, Whq, bh, aggA, aggB, nullptr, nullptr);
            scan_p2_kernel<<<dim3(D), 256, 0, stream>>>(
                aggA, aggB, hini, (float*)d_out, 1, NCH);
            break;
        }

        // forward: aggregate -> inter-chunk scan -> replay, write h_f to qnext
        qrn_gemm_kernel<1,0><<<gGrid, 256, 0, stream>>>(
            story, qcur, Wz, bz, Whx, Whq, bh, aggA, aggB, nullptr, nullptr);
        scan_p2_kernel<<<dim3(D), 256, 0, stream>>>(aggA, aggB, hini, nullptr, 1, NCH);
        qrn_gemm_kernel<1,1><<<gGrid, 256, 0, stream>>>(
            story, qcur, Wz, bz, Whx, Whq, bh, nullptr, nullptr, hini, qnext);

        // backward: same with reversed processing order; accumulates into qnext
        const float* Wzb  = Wz_b + (size_t)l * D * D;
        const float* bzb  = bz_b + (size_t)l * D;
        const float* Whxb = Wh_b + (size_t)l * 2 * D * D;
        const float* Whqb = Whxb + (size_t)D * D;
        const float* bhb  = bh_b + (size_t)l * D;

        qrn_gemm_kernel<0,0><<<gGrid, 256, 0, stream>>>(
            story, qcur, Wzb, bzb, Whxb, Whqb, bhb, aggA, aggB, nullptr, nullptr);
        scan_p2_kernel<<<dim3(D), 256, 0, stream>>>(aggA, aggB, hini, nullptr, 0, NCH);
        qrn_gemm_kernel<0,1><<<gGrid, 256, 0, stream>>>(
            story, qcur, Wzb, bzb, Whxb, Whqb, bhb, nullptr, nullptr, hini, qnext);

        // ping-pong
        const u16* t = qcur; qcur = qnext; qnext = (u16*)t;
    }
}

// Round 3
// 1184.080 us; speedup vs baseline: 3.7533x; 3.7533x over previous
//
#include <hip/hip_runtime.h>
#include <hip/hip_bf16.h>
#include <math.h>

#define D    256
#define BT   128     // chunk length == M tile
#define BN   64      // N tile
#define KP   40      // padded LDS K-stride (shorts): 32 data + 8 pad
#define NSEG 32      // BT/4 segments per chunk

typedef unsigned short u16;
typedef __attribute__((ext_vector_type(8))) short short8;   // 8 bf16 = 4 VGPRs
typedef __attribute__((ext_vector_type(4))) float floatx4;  // MFMA C/D frag

__device__ __forceinline__ float b2f(u16 v) {
    union { unsigned u; float f; } x; x.u = ((unsigned)v) << 16; return x.f;
}
__device__ __forceinline__ u16 f2b(float f) {
    union { unsigned u; float f; } x; x.f = f;
    unsigned lsb = (x.u >> 16) & 1;
    x.u += 0x7fffu + lsb;                 // RNE
    return (u16)(x.u >> 16);
}
__device__ __forceinline__ float sigm(float x) {
    return __builtin_amdgcn_rcpf(1.0f + __expf(-x));
}
__device__ __forceinline__ float tanhfast(float x) {
    // tanh(x) = 1 - 2/(e^{2x}+1); robust at +-inf
    return 1.0f - 2.0f * __builtin_amdgcn_rcpf(__expf(2.0f * x) + 1.0f);
}

// ---------------------------------------------------------------------------
// weight transpose + bf16 cast: wt[combo][m][n][k] = bf16(W[k][n])
// combo: 0..2 = fwd layer l; 3..4 = bwd layer l. m: 0=Wz, 1=Whx, 2=Whq.
// ---------------------------------------------------------------------------
__global__ __launch_bounds__(256) void wtrans_kernel(
    const float* __restrict__ Wz_f, const float* __restrict__ Wh_f,
    const float* __restrict__ Wz_b, const float* __restrict__ Wh_b,
    u16* __restrict__ wt)
{
    int id = blockIdx.x * 256 + threadIdx.x;       // < 5*3*65536
    int combo = id / (3 * 65536);
    int rem   = id % (3 * 65536);
    int m = rem >> 16;
    int e = rem & 65535;
    int k = e >> 8, n = e & 255;                   // consecutive id -> n contiguous (coalesced reads)
    int l   = combo < 3 ? combo : combo - 3;
    int dir = combo < 3 ? 0 : 1;
    float v;
    if (m == 0) {
        const float* Wz = dir ? Wz_b : Wz_f;
        v = Wz[((size_t)l * D + k) * D + n];
    } else {
        const float* Wh = dir ? Wh_b : Wh_f;
        int kk = (m == 2) ? (k + D) : k;
        v = Wh[((size_t)l * 2 * D + kk) * D + n];
    }
    wt[(size_t)combo * 3 * 65536 + (size_t)m * 65536 + (size_t)n * D + k] = f2b(v);
}

// ---------------------------------------------------------------------------
// q_init: q[t][d] = bf16(question[d])
// ---------------------------------------------------------------------------
__global__ __launch_bounds__(256) void q_init_kernel(
    u16* __restrict__ q, const float* __restrict__ question, long total4)
{
    long i = (long)blockIdx.x * 256 + threadIdx.x;
    if (i < total4) {
        int col = (int)(i & (D/4 - 1)) * 4;
        ushort4 v;
        v.x = f2b(question[col + 0]);
        v.y = f2b(question[col + 1]);
        v.z = f2b(question[col + 2]);
        v.w = f2b(question[col + 3]);
        *(ushort4*)(q + i * 4) = v;
    }
}

// ---------------------------------------------------------------------------
// Fused bf16-MFMA gates-GEMM + chunk scan.
// Block = (chunk c of 128 timesteps) x (64-channel slice). 4 waves, each
// 32 rows x 64 cols = 2x4 tiles of 16x16x32 MFMA, BK=32 slices of K=256.
//   gz = (x.q)@Wz ; gh = x@Whx + q@Whq   (weights pre-transposed [n][k] bf16)
//   a = 1-sigmoid(gz+bz) ; b = sigmoid(gz+bz)*tanh(gh+bh)
// PHASE 0: per-chunk affine aggregate -> aggA/aggB
// PHASE 1: replay from hinit; FWD writes bf16 h, BWD accumulates h into hout.
// ---------------------------------------------------------------------------
struct StageS {
    short ax [BT][KP]; short aq [BT][KP]; short axq[BT][KP];
    short bz_[BN][KP]; short bx_[BN][KP]; short bq_[BN][KP];
};
struct EpiS {
    float segA[NSEG][BN]; float segB[NSEG][BN]; float hseg[NSEG][BN];
    u16   hout[BT][BN];
};
union SharedU { StageS st; EpiS ep; };

template<int FWD, int PHASE>
__global__ __launch_bounds__(256) void qrn_gemm(
    const float* __restrict__ x, const u16* __restrict__ qg,
    const u16* __restrict__ wt,                 // combo base: 3*D*D bf16 [n][k]
    const float* __restrict__ bz, const float* __restrict__ bh,
    float* __restrict__ aggA, float* __restrict__ aggB,
    const float* __restrict__ hinit, u16* __restrict__ hout)
{
    __shared__ SharedU sh;
    const int tid  = threadIdx.x;
    const int c    = (int)(blockIdx.x >> 2);
    const int n0   = (int)(blockIdx.x & 3) * BN;
    const int t0   = c * BT;
    const int lane = tid & 63, w = tid >> 6;
    const int lr   = lane & 15, quad = lane >> 4;

    floatx4 accz[2][4], acch[2][4];
    #pragma unroll
    for (int rt = 0; rt < 2; ++rt)
        #pragma unroll
        for (int ct = 0; ct < 4; ++ct) {
            accz[rt][ct] = (floatx4){0.f,0.f,0.f,0.f};
            acch[rt][ct] = (floatx4){0.f,0.f,0.f,0.f};
        }

    const u16* wz = wt;
    const u16* wx = wt + 65536;
    const u16* wq = wt + 131072;

    for (int k0 = 0; k0 < D; k0 += 32) {
        // ---- stage A: x (fp32->bf16), q (copy), xq (fp32 product->bf16)
        #pragma unroll
        for (int s = 0; s < 2; ++s) {
            int id = tid + 256 * s;               // 0..511
            int r = id >> 2, g = id & 3;
            const float* xp = x + (size_t)(t0 + r) * D + k0 + g * 8;
            float4 xa = *(const float4*)xp;
            float4 xb = *(const float4*)(xp + 4);
            short8 q8 = *(const short8*)(qg + (size_t)(t0 + r) * D + k0 + g * 8);
            float xf[8] = {xa.x, xa.y, xa.z, xa.w, xb.x, xb.y, xb.z, xb.w};
            short8 x8, xq8;
            #pragma unroll
            for (int i = 0; i < 8; ++i) {
                float qf = b2f((u16)q8[i]);
                x8[i]  = (short)f2b(xf[i]);
                xq8[i] = (short)f2b(xf[i] * qf);
            }
            *(short8*)&sh.st.ax [r][g * 8] = x8;
            *(short8*)&sh.st.aq [r][g * 8] = q8;
            *(short8*)&sh.st.axq[r][g * 8] = xq8;
        }
        // ---- stage B: 3 weight mats, [n][k] bf16 copy
        #pragma unroll
        for (int s = 0; s < 3; ++s) {
            int id = tid + 256 * s;               // 0..767
            int m = id >> 8, rem = id & 255;
            int n = rem >> 2, g = rem & 3;
            const u16* wp = (m == 0 ? wz : m == 1 ? wx : wq) + (size_t)(n0 + n) * D + k0 + g * 8;
            short8 w8 = *(const short8*)wp;
            short* dst = (m == 0 ? &sh.st.bz_[0][0] : m == 1 ? &sh.st.bx_[0][0] : &sh.st.bq_[0][0]);
            *(short8*)(dst + n * KP + g * 8) = w8;
        }
        __syncthreads();

        // ---- MFMA: A frags (rows w*32+rt*16+lr, k quad*8), B frags ([n][k])
        short8 fx[2], fq[2], fxq[2];
        #pragma unroll
        for (int rt = 0; rt < 2; ++rt) {
            int row = w * 32 + rt * 16 + lr;
            fx [rt] = *(const short8*)&sh.st.ax [row][quad * 8];
            fq [rt] = *(const short8*)&sh.st.aq [row][quad * 8];
            fxq[rt] = *(const short8*)&sh.st.axq[row][quad * 8];
        }
        #pragma unroll
        for (int ct = 0; ct < 4; ++ct) {
            int bn = ct * 16 + lr;
            short8 vz = *(const short8*)&sh.st.bz_[bn][quad * 8];
            short8 vx = *(const short8*)&sh.st.bx_[bn][quad * 8];
            short8 vq = *(const short8*)&sh.st.bq_[bn][quad * 8];
            #pragma unroll
            for (int rt = 0; rt < 2; ++rt) {
                accz[rt][ct] = __builtin_amdgcn_mfma_f32_16x16x32_bf16(fxq[rt], vz, accz[rt][ct], 0, 0, 0);
                acch[rt][ct] = __builtin_amdgcn_mfma_f32_16x16x32_bf16(fx [rt], vx, acch[rt][ct], 0, 0, 0);
                acch[rt][ct] = __builtin_amdgcn_mfma_f32_16x16x32_bf16(fq [rt], vq, acch[rt][ct], 0, 0, 0);
            }
        }
        __syncthreads();
    }

    // ---- gate epilogue (C/D layout: col = lr, rows = quad*4 + r)
    float av[2][4][4], bv[2][4][4];
    #pragma unroll
    for (int ct = 0; ct < 4; ++ct) {
        int n = n0 + ct * 16 + lr;
        float bzn = bz[n], bhn = bh[n];
        #pragma unroll
        for (int rt = 0; rt < 2; ++rt)
            #pragma unroll
            for (int r = 0; r < 4; ++r) {
                float z  = sigm(accz[rt][ct][r] + bzn);
                float ht = tanhfast(acch[rt][ct][r] + bhn);
                av[rt][ct][r] = 1.0f - z;
                bv[rt][ct][r] = z * ht;
            }
    }

    // ---- per-lane 4-step segment aggregates (rows are consecutive in r!)
    #pragma unroll
    for (int rt = 0; rt < 2; ++rt)
        #pragma unroll
        for (int ct = 0; ct < 4; ++ct) {
            float A = 1.f, B = 0.f;
            if (FWD) {
                #pragma unroll
                for (int r = 0; r < 4; ++r) { A = av[rt][ct][r] * A; B = fmaf(av[rt][ct][r], B, bv[rt][ct][r]); }
            } else {
                #pragma unroll
                for (int r = 3; r >= 0; --r) { A = av[rt][ct][r] * A; B = fmaf(av[rt][ct][r], B, bv[rt][ct][r]); }
            }
            int seg = w * 8 + rt * 4 + quad;
            int col = ct * 16 + lr;
            sh.ep.segA[seg][col] = A;
            sh.ep.segB[seg][col] = B;
        }
    __syncthreads();

    if (PHASE == 0) {
        if (tid < BN) {
            float A = 1.f, B = 0.f;
            if (FWD) {
                #pragma unroll
                for (int sg = 0; sg < NSEG; ++sg) {
                    float a = sh.ep.segA[sg][tid];
                    A = a * A; B = fmaf(a, B, sh.ep.segB[sg][tid]);
                }
            } else {
                #pragma unroll
                for (int sg = NSEG - 1; sg >= 0; --sg) {
                    float a = sh.ep.segA[sg][tid];
                    A = a * A; B = fmaf(a, B, sh.ep.segB[sg][tid]);
                }
            }
            aggA[(size_t)c * D + n0 + tid] = A;
            aggB[(size_t)c * D + n0 + tid] = B;
        }
    } else {
        if (tid < BN) {
            float h = hinit[(size_t)c * D + n0 + tid];
            if (FWD) {
                #pragma unroll
                for (int sg = 0; sg < NSEG; ++sg) {
                    sh.ep.hseg[sg][tid] = h;
                    h = fmaf(sh.ep.segA[sg][tid], h, sh.ep.segB[sg][tid]);
                }
            } else {
                #pragma unroll
                for (int sg = NSEG - 1; sg >= 0; --sg) {
                    sh.ep.hseg[sg][tid] = h;
                    h = fmaf(sh.ep.segA[sg][tid], h, sh.ep.segB[sg][tid]);
                }
            }
        }
        __syncthreads();
        // replay 4 rows per (rt,ct), park h in LDS for coalesced writeout
        #pragma unroll
        for (int rt = 0; rt < 2; ++rt)
            #pragma unroll
            for (int ct = 0; ct < 4; ++ct) {
                int seg = w * 8 + rt * 4 + quad;
                int col = ct * 16 + lr;
                float h = sh.ep.hseg[seg][col];
                if (FWD) {
                    #pragma unroll
                    for (int r = 0; r < 4; ++r) {
                        h = fmaf(av[rt][ct][r], h, bv[rt][ct][r]);
                        sh.ep.hout[w * 32 + rt * 16 + quad * 4 + r][col] = f2b(h);
                    }
                } else {
                    #pragma unroll
                    for (int r = 3; r >= 0; --r) {
                        h = fmaf(av[rt][ct][r], h, bv[rt][ct][r]);
                        sh.ep.hout[w * 32 + rt * 16 + quad * 4 + r][col] = f2b(h);
                    }
                }
            }
        __syncthreads();
        // coalesced copy-out (FWD: store; BWD: accumulate into existing)
        #pragma unroll
        for (int s = 0; s < 4; ++s) {
            int id = tid + 256 * s;               // 0..1023
            int r = id >> 3, g = id & 7;
            short8 hv = *(const short8*)&sh.ep.hout[r][g * 8];
            u16* gp = hout + (size_t)(t0 + r) * D + n0 + g * 8;
            if (FWD) {
                *(short8*)gp = hv;
            } else {
                short8 old = *(const short8*)gp;
                short8 nv;
                #pragma unroll
                for (int i = 0; i < 8; ++i)
                    nv[i] = (short)f2b(b2f((u16)old[i]) + b2f((u16)hv[i]));
                *(short8*)gp = nv;
            }
        }
    }
}

// ---------------------------------------------------------------------------
// inter-chunk scan: one block per channel, Hillis-Steele over NCH=512 chunk
// aggregates in processing order. hinit may alias aggB (all agg values are
// register-resident before the hinit writes).
// ---------------------------------------------------------------------------
__global__ __launch_bounds__(256) void scan_p2_kernel(
    const float* __restrict__ aggA, const float* __restrict__ aggB,
    float* __restrict__ hinit, float* __restrict__ out_final, int fwd, int nch)
{
    __shared__ float sA[256], sB[256];
    const int n = blockIdx.x, tid = threadIdx.x;
    const int per = nch >> 8;                    // 2
    float lA[4], lB[4];
    float A = 1.f, B = 0.f;
    for (int j = 0; j < per; ++j) {
        int p = tid * per + j;
        int c = fwd ? p : (nch - 1 - p);
        float a = aggA[(size_t)c * D + n];
        float b = aggB[(size_t)c * D + n];
        lA[j] = a; lB[j] = b;
        A = a * A;
        B = fmaf(a, B, b);
    }
    sA[tid] = A; sB[tid] = B;
    __syncthreads();
    for (int off = 1; off < 256; off <<= 1) {
        float pA = 1.f, pB = 0.f;
        if (tid >= off) { pA = sA[tid - off]; pB = sB[tid - off]; }
        __syncthreads();
        if (tid >= off) {
            float cA = sA[tid], cB = sB[tid];
            sA[tid] = pA * cA;
            sB[tid] = fmaf(cA, pB, cB);
        }
        __syncthreads();
    }
    float eB = (tid > 0) ? sB[tid - 1] : 0.f;
    for (int j = 0; j < per; ++j) {
        int p = tid * per + j;
        int c = fwd ? p : (nch - 1 - p);
        hinit[(size_t)c * D + n] = eB;
        eB = fmaf(lA[j], eB, lB[j]);
    }
    if (out_final != nullptr && tid == 0) out_final[n] = sB[255];
}

// ---------------------------------------------------------------------------
extern "C" void kernel_launch(void* const* d_in, const int* in_sizes, int n_in,
                              void* d_out, int out_size, void* d_ws, size_t ws_size,
                              hipStream_t stream) {
    const float* story    = (const float*)d_in[0];
    const float* question = (const float*)d_in[1];
    const float* Wz_f = (const float*)d_in[2];
    const float* bz_f = (const float*)d_in[3];
    const float* Wh_f = (const float*)d_in[4];
    const float* bh_f = (const float*)d_in[5];
    const float* Wz_b = (const float*)d_in[6];
    const float* bz_b = (const float*)d_in[7];
    const float* Wh_b = (const float*)d_in[8];
    const float* bh_b = (const float*)d_in[9];

    const int T    = in_sizes[0] / D;            // 65536
    const int NCH  = T / BT;                     // 512
    const size_t TD = (size_t)T * D;

    // workspace (~66.9 MiB): qA/qB bf16 ping-pong, wt (5 combos x 3 mats),
    // aggA, aggB (hinit aliases aggB)
    u16*   qA   = (u16*)d_ws;
    u16*   qB   = qA + TD;
    u16*   wt   = qB + TD;                       // 5*3*65536 bf16
    float* aggA = (float*)(wt + 5 * 3 * 65536);
    float* aggB = aggA + (size_t)NCH * D;
    float* hini = aggB;                          // alias (safe, see scan_p2)

    // prep: weight transpose+cast, q broadcast
    wtrans_kernel<<<dim3(5 * 3 * 65536 / 256), dim3(256), 0, stream>>>(
        Wz_f, Wh_f, Wz_b, Wh_b, wt);
    {
        long total4 = (long)(TD / 4);
        q_init_kernel<<<dim3((unsigned)(total4 / 256)), dim3(256), 0, stream>>>(
            qA, question, total4);
    }

    const u16* qcur  = qA;
    u16*       qnext = qB;
    dim3 gGrid((unsigned)(NCH * 4));             // 2048 blocks

    for (int l = 0; l < 3; ++l) {
        const u16*   wtf = wt + (size_t)l * 3 * 65536;          // fwd combo
        const float* bzf = bz_f + (size_t)l * D;
        const float* bhf = bh_f + (size_t)l * D;

        if (l == 2) {
            qrn_gemm<1,0><<<gGrid, 256, 0, stream>>>(
                story, qcur, wtf, bzf, bhf, aggA, aggB, nullptr, nullptr);
            scan_p2_kernel<<<dim3(D), 256, 0, stream>>>(
                aggA, aggB, hini, (float*)d_out, 1, NCH);
            break;
        }

        // forward
        qrn_gemm<1,0><<<gGrid, 256, 0, stream>>>(
            story, qcur, wtf, bzf, bhf, aggA, aggB, nullptr, nullptr);
        scan_p2_kernel<<<dim3(D), 256, 0, stream>>>(aggA, aggB, hini, nullptr, 1, NCH);
        qrn_gemm<1,1><<<gGrid, 256, 0, stream>>>(
            story, qcur, wtf, bzf, bhf, nullptr, nullptr, hini, qnext);

        // backward (reversed processing order; accumulates into qnext)
        const u16*   wtb = wt + (size_t)(3 + l) * 3 * 65536;    // bwd combo
        const float* bzb = bz_b + (size_t)l * D;
        const float* bhb = bh_b + (size_t)l * D;

        qrn_gemm<0,0><<<gGrid, 256, 0, stream>>>(
            story, qcur, wtb, bzb, bhb, aggA, aggB, nullptr, nullptr);
        scan_p2_kernel<<<dim3(D), 256, 0, stream>>>(aggA, aggB, hini, nullptr, 0, NCH);
        qrn_gemm<0,1><<<gGrid, 256, 0, stream>>>(
            story, qcur, wtb, bzb, bhb, nullptr, nullptr, hini, qnext);

        const u16* tswap = qcur; qcur = qnext; qnext = (u16*)tswap;
    }
}

// Round 4
// 973.446 us; speedup vs baseline: 4.5654x; 1.2164x over previous
//
#include <hip/hip_runtime.h>
#include <hip/hip_bf16.h>
#include <math.h>

#define D    256
#define BT   128     // chunk length == M tile
#define BN   64      // N tile per block (4 N-slices)
#define NSEG 32      // BT/4 segments per chunk

typedef unsigned short u16;
typedef __attribute__((ext_vector_type(8))) short short8;   // 8 bf16 = 4 VGPRs
typedef __attribute__((ext_vector_type(4))) float floatx4;  // MFMA C/D frag

__device__ __forceinline__ float b2f(u16 v) {
    union { unsigned u; float f; } x; x.u = ((unsigned)v) << 16; return x.f;
}
__device__ __forceinline__ u16 f2b(float f) {
    union { unsigned u; float f; } x; x.f = f;
    unsigned lsb = (x.u >> 16) & 1;
    x.u += 0x7fffu + lsb;                 // RNE
    return (u16)(x.u >> 16);
}
__device__ __forceinline__ float sigm(float x) {
    return __builtin_amdgcn_rcpf(1.0f + __expf(-x));
}
__device__ __forceinline__ float tanhfast(float x) {
    return 1.0f - 2.0f * __builtin_amdgcn_rcpf(__expf(2.0f * x) + 1.0f);
}
// async global->LDS, 16B per lane; lds ptr must be wave-uniform (HW adds lane*16)
__device__ __forceinline__ void async16(const u16* g, u16* l) {
    __builtin_amdgcn_global_load_lds(
        (const __attribute__((address_space(1))) unsigned int*)g,
        (__attribute__((address_space(3))) unsigned int*)l, 16, 0, 0);
}

// ---------------------------------------------------------------------------
// weight transpose + bf16 cast: wt[combo][m][n][k] = bf16(W[k][n])
// combo: 0..2 = fwd layer l; 3..4 = bwd layer (l<2). m: 0=Wz, 1=Whx, 2=Whq.
// ---------------------------------------------------------------------------
__global__ __launch_bounds__(256) void wtrans_kernel(
    const float* __restrict__ Wz_f, const float* __restrict__ Wh_f,
    const float* __restrict__ Wz_b, const float* __restrict__ Wh_b,
    u16* __restrict__ wt)
{
    int id = blockIdx.x * 256 + threadIdx.x;       // < 5*3*65536
    int combo = id / (3 * 65536);
    int rem   = id % (3 * 65536);
    int m = rem >> 16;
    int e = rem & 65535;
    int k = e >> 8, n = e & 255;
    int l   = combo < 3 ? combo : combo - 3;
    int dir = combo < 3 ? 0 : 1;
    float v;
    if (m == 0) {
        const float* Wz = dir ? Wz_b : Wz_f;
        v = Wz[((size_t)l * D + k) * D + n];
    } else {
        const float* Wh = dir ? Wh_b : Wh_f;
        int kk = (m == 2) ? (k + D) : k;
        v = Wh[((size_t)l * 2 * D + kk) * D + n];
    }
    wt[(size_t)combo * 3 * 65536 + (size_t)m * 65536 + (size_t)n * D + k] = f2b(v);
}

// ---------------------------------------------------------------------------
// Tier A prep: xb = bf16(x), q = bf16(question) broadcast, xq = bf16(x*qbf)
// one thread per 8 elements
// ---------------------------------------------------------------------------
__global__ __launch_bounds__(256) void prep0_kernel(
    const float* __restrict__ story, const float* __restrict__ question,
    u16* __restrict__ xb, u16* __restrict__ q, u16* __restrict__ xq)
{
    long id = (long)blockIdx.x * 256 + threadIdx.x;
    long row = id >> 5;
    int  d0  = (int)(id & 31) * 8;
    const float* xp = story + row * D + d0;
    float4 xa = *(const float4*)xp;
    float4 xc = *(const float4*)(xp + 4);
    float xv[8] = {xa.x, xa.y, xa.z, xa.w, xc.x, xc.y, xc.z, xc.w};
    short8 xs, qs, xqs;
    #pragma unroll
    for (int i = 0; i < 8; ++i) {
        u16 qb = f2b(question[d0 + i]);
        xs[i]  = (short)f2b(xv[i]);
        qs[i]  = (short)qb;
        xqs[i] = (short)f2b(xv[i] * b2f(qb));
    }
    long o = id * 8;
    *(short8*)(xb + o) = xs;
    *(short8*)(q  + o) = qs;
    *(short8*)(xq + o) = xqs;
}

// Tier B prep: q broadcast only
__global__ __launch_bounds__(256) void q_init_kernel(
    u16* __restrict__ q, const float* __restrict__ question, long total8)
{
    long id = (long)blockIdx.x * 256 + threadIdx.x;
    if (id < total8) {
        int d0 = (int)(id & 31) * 8;
        short8 v;
        #pragma unroll
        for (int i = 0; i < 8; ++i) v[i] = (short)f2b(question[d0 + i]);
        *(short8*)(q + id * 8) = v;
    }
}

// Tier A: xq = bf16(b2f(xb) * b2f(qnew)) after each layer's q update
__global__ __launch_bounds__(256) void xq_upd_kernel(
    const u16* __restrict__ xb, const u16* __restrict__ qn, u16* __restrict__ xq)
{
    long id = (long)blockIdx.x * 256 + threadIdx.x;
    long o  = id * 8;
    short8 xs = *(const short8*)(xb + o);
    short8 qs = *(const short8*)(qn + o);
    short8 r;
    #pragma unroll
    for (int i = 0; i < 8; ++i)
        r[i] = (short)f2b(b2f((u16)xs[i]) * b2f((u16)qs[i]));
    *(short8*)(xq + o) = r;
}

// ---------------------------------------------------------------------------
// Fused bf16-MFMA gates-GEMM + chunk scan.
// LDS A/B tiles laid out [row][32k] (64B rows) with XOR slot swizzle:
// 16B group at slot s holds data group g = s ^ ((row>>1)&3)  -> all LDS
// reads/writes are <=2-way per bank (free).
// ASY=1: x/q/xq all staged via global_load_lds (zero staging VALU).
// ASY=0: x fp32 + q bf16 via VGPR, xq computed in stager (tier B).
// ---------------------------------------------------------------------------
struct StageS {
    u16 ax [BT * 32]; u16 aq [BT * 32]; u16 axq[BT * 32];   // 8KB each
    u16 bz_[BN * 32]; u16 bx_[BN * 32]; u16 bq_[BN * 32];   // 4KB each
};
struct EpiS {
    float segA[NSEG][BN]; float segB[NSEG][BN]; float hseg[NSEG][BN];
    u16   hout[BT][BN];
};
union SharedU { StageS st; EpiS ep; };

template<int FWD, int PHASE, int ASY>
__global__ __launch_bounds__(256) void qrn_gemm(
    const float* __restrict__ xf,               // tier B: fp32 story
    const u16* __restrict__ xbg,                // tier A: bf16 story
    const u16* __restrict__ qg,
    const u16* __restrict__ xqg,                // tier A: bf16 x*q
    const u16* __restrict__ wt,                 // combo base: 3*D*D bf16 [n][k]
    const float* __restrict__ bz, const float* __restrict__ bh,
    float* __restrict__ aggA, float* __restrict__ aggB,
    const float* __restrict__ hinit, u16* __restrict__ hout)
{
    __shared__ SharedU sh;
    const int tid  = threadIdx.x;
    // XCD swizzle: 4 N-slices of a chunk land on the same XCD (bid%8 = XCD)
    const int gidx = ((int)blockIdx.x & 7) * 256 + ((int)blockIdx.x >> 3);
    const int c    = gidx >> 2;
    const int n0   = (gidx & 3) * BN;
    const int t0   = c * BT;
    const int lane = tid & 63, w = tid >> 6;
    const int lr   = lane & 15, quad = lane >> 4;

    // fragment LDS offsets (shorts), constant across k-slices
    int offA[2], offB[4];
    #pragma unroll
    for (int rt = 0; rt < 2; ++rt) {
        int row = w * 32 + rt * 16 + lr;
        offA[rt] = row * 32 + (quad ^ ((row >> 1) & 3)) * 8;
    }
    #pragma unroll
    for (int ct = 0; ct < 4; ++ct) {
        int n = ct * 16 + lr;
        offB[ct] = n * 32 + (quad ^ ((n >> 1) & 3)) * 8;
    }

    floatx4 accz[2][4], acch[2][4];
    #pragma unroll
    for (int rt = 0; rt < 2; ++rt)
        #pragma unroll
        for (int ct = 0; ct < 4; ++ct) {
            accz[rt][ct] = (floatx4){0.f,0.f,0.f,0.f};
            acch[rt][ct] = (floatx4){0.f,0.f,0.f,0.f};
        }

    const u16* wz = wt;
    const u16* wx = wt + 65536;
    const u16* wq = wt + 131072;
    const int wbase = (tid & ~63) * 8;          // wave-uniform lds base (shorts)

    for (int k0 = 0; k0 < D; k0 += 32) {
        if (ASY) {
            #pragma unroll
            for (int i = 0; i < 2; ++i) {
                int u = i * 256 + tid;
                int row = u >> 2, sl = u & 3;
                int gg = sl ^ ((row >> 1) & 3);
                size_t go = (size_t)(t0 + row) * D + k0 + gg * 8;
                int lb = (i * 256 + (tid & ~63)) * 8;
                async16(xbg + go, sh.st.ax  + lb);
                async16(qg  + go, sh.st.aq  + lb);
                async16(xqg + go, sh.st.axq + lb);
            }
        } else {
            #pragma unroll
            for (int i = 0; i < 2; ++i) {
                int id = i * 256 + tid;
                int row = id >> 2, sl = id & 3;
                int gg = sl ^ ((row >> 1) & 3);
                const float* xp = xf + (size_t)(t0 + row) * D + k0 + gg * 8;
                float4 xa = *(const float4*)xp;
                float4 xc = *(const float4*)(xp + 4);
                short8 q8 = *(const short8*)(qg + (size_t)(t0 + row) * D + k0 + gg * 8);
                float xv[8] = {xa.x, xa.y, xa.z, xa.w, xc.x, xc.y, xc.z, xc.w};
                short8 x8, xq8;
                #pragma unroll
                for (int e = 0; e < 8; ++e) {
                    float qf = b2f((u16)q8[e]);
                    x8[e]  = (short)f2b(xv[e]);
                    xq8[e] = (short)f2b(xv[e] * qf);
                }
                int lb = id * 8;
                *(short8*)(sh.st.ax  + lb) = x8;
                *(short8*)(sh.st.aq  + lb) = q8;
                *(short8*)(sh.st.axq + lb) = xq8;
            }
        }
        // B streams: always async
        {
            int n = tid >> 2, sl = tid & 3;
            int gg = sl ^ ((n >> 1) & 3);
            size_t go = (size_t)(n0 + n) * D + k0 + gg * 8;
            async16(wz + go, sh.st.bz_ + wbase);
            async16(wx + go, sh.st.bx_ + wbase);
            async16(wq + go, sh.st.bq_ + wbase);
        }
        __syncthreads();

        short8 fx[2], fq[2], fxq[2];
        #pragma unroll
        for (int rt = 0; rt < 2; ++rt) {
            fx [rt] = *(const short8*)(sh.st.ax  + offA[rt]);
            fq [rt] = *(const short8*)(sh.st.aq  + offA[rt]);
            fxq[rt] = *(const short8*)(sh.st.axq + offA[rt]);
        }
        #pragma unroll
        for (int ct = 0; ct < 4; ++ct) {
            short8 vz = *(const short8*)(sh.st.bz_ + offB[ct]);
            short8 vx = *(const short8*)(sh.st.bx_ + offB[ct]);
            short8 vq = *(const short8*)(sh.st.bq_ + offB[ct]);
            #pragma unroll
            for (int rt = 0; rt < 2; ++rt) {
                accz[rt][ct] = __builtin_amdgcn_mfma_f32_16x16x32_bf16(fxq[rt], vz, accz[rt][ct], 0, 0, 0);
                acch[rt][ct] = __builtin_amdgcn_mfma_f32_16x16x32_bf16(fx [rt], vx, acch[rt][ct], 0, 0, 0);
                acch[rt][ct] = __builtin_amdgcn_mfma_f32_16x16x32_bf16(fq [rt], vq, acch[rt][ct], 0, 0, 0);
            }
        }
        __syncthreads();
    }

    // ---- gate epilogue (C/D: col = lr, rows = quad*4 + r)
    float av[2][4][4], bv[2][4][4];
    #pragma unroll
    for (int ct = 0; ct < 4; ++ct) {
        int n = n0 + ct * 16 + lr;
        float bzn = bz[n], bhn = bh[n];
        #pragma unroll
        for (int rt = 0; rt < 2; ++rt)
            #pragma unroll
            for (int r = 0; r < 4; ++r) {
                float z  = sigm(accz[rt][ct][r] + bzn);
                float ht = tanhfast(acch[rt][ct][r] + bhn);
                av[rt][ct][r] = 1.0f - z;
                bv[rt][ct][r] = z * ht;
            }
    }

    // ---- per-lane 4-step segment aggregates
    #pragma unroll
    for (int rt = 0; rt < 2; ++rt)
        #pragma unroll
        for (int ct = 0; ct < 4; ++ct) {
            float A = 1.f, B = 0.f;
            if (FWD) {
                #pragma unroll
                for (int r = 0; r < 4; ++r) { A = av[rt][ct][r] * A; B = fmaf(av[rt][ct][r], B, bv[rt][ct][r]); }
            } else {
                #pragma unroll
                for (int r = 3; r >= 0; --r) { A = av[rt][ct][r] * A; B = fmaf(av[rt][ct][r], B, bv[rt][ct][r]); }
            }
            int seg = w * 8 + rt * 4 + quad;
            int col = ct * 16 + lr;
            sh.ep.segA[seg][col] = A;
            sh.ep.segB[seg][col] = B;
        }
    __syncthreads();

    if (PHASE == 0) {
        if (tid < BN) {
            float A = 1.f, B = 0.f;
            if (FWD) {
                #pragma unroll
                for (int sg = 0; sg < NSEG; ++sg) {
                    float a = sh.ep.segA[sg][tid];
                    A = a * A; B = fmaf(a, B, sh.ep.segB[sg][tid]);
                }
            } else {
                #pragma unroll
                for (int sg = NSEG - 1; sg >= 0; --sg) {
                    float a = sh.ep.segA[sg][tid];
                    A = a * A; B = fmaf(a, B, sh.ep.segB[sg][tid]);
                }
            }
            aggA[(size_t)c * D + n0 + tid] = A;
            aggB[(size_t)c * D + n0 + tid] = B;
        }
    } else {
        if (tid < BN) {
            float h = hinit[(size_t)c * D + n0 + tid];
            if (FWD) {
                #pragma unroll
                for (int sg = 0; sg < NSEG; ++sg) {
                    sh.ep.hseg[sg][tid] = h;
                    h = fmaf(sh.ep.segA[sg][tid], h, sh.ep.segB[sg][tid]);
                }
            } else {
                #pragma unroll
                for (int sg = NSEG - 1; sg >= 0; --sg) {
                    sh.ep.hseg[sg][tid] = h;
                    h = fmaf(sh.ep.segA[sg][tid], h, sh.ep.segB[sg][tid]);
                }
            }
        }
        __syncthreads();
        #pragma unroll
        for (int rt = 0; rt < 2; ++rt)
            #pragma unroll
            for (int ct = 0; ct < 4; ++ct) {
                int seg = w * 8 + rt * 4 + quad;
                int col = ct * 16 + lr;
                float h = sh.ep.hseg[seg][col];
                if (FWD) {
                    #pragma unroll
                    for (int r = 0; r < 4; ++r) {
                        h = fmaf(av[rt][ct][r], h, bv[rt][ct][r]);
                        sh.ep.hout[w * 32 + rt * 16 + quad * 4 + r][col] = f2b(h);
                    }
                } else {
                    #pragma unroll
                    for (int r = 3; r >= 0; --r) {
                        h = fmaf(av[rt][ct][r], h, bv[rt][ct][r]);
                        sh.ep.hout[w * 32 + rt * 16 + quad * 4 + r][col] = f2b(h);
                    }
                }
            }
        __syncthreads();
        #pragma unroll
        for (int s = 0; s < 4; ++s) {
            int id = tid + 256 * s;
            int r = id >> 3, g = id & 7;
            short8 hv = *(const short8*)&sh.ep.hout[r][g * 8];
            u16* gp = hout + (size_t)(t0 + r) * D + n0 + g * 8;
            if (FWD) {
                *(short8*)gp = hv;
            } else {
                short8 old = *(const short8*)gp;
                short8 nv;
                #pragma unroll
                for (int i = 0; i < 8; ++i)
                    nv[i] = (short)f2b(b2f((u16)old[i]) + b2f((u16)hv[i]));
                *(short8*)gp = nv;
            }
        }
    }
}

// ---------------------------------------------------------------------------
// inter-chunk scan: one block per channel, Hillis-Steele over NCH=512 chunk
// aggregates. hinit may alias aggB (agg values register-resident first).
// ---------------------------------------------------------------------------
__global__ __launch_bounds__(256) void scan_p2_kernel(
    const float* __restrict__ aggA, const float* __restrict__ aggB,
    float* __restrict__ hinit, float* __restrict__ out_final, int fwd, int nch)
{
    __shared__ float sA[256], sB[256];
    const int n = blockIdx.x, tid = threadIdx.x;
    const int per = nch >> 8;                    // 2
    float lA[4], lB[4];
    float A = 1.f, B = 0.f;
    for (int j = 0; j < per; ++j) {
        int p = tid * per + j;
        int c = fwd ? p : (nch - 1 - p);
        float a = aggA[(size_t)c * D + n];
        float b = aggB[(size_t)c * D + n];
        lA[j] = a; lB[j] = b;
        A = a * A;
        B = fmaf(a, B, b);
    }
    sA[tid] = A; sB[tid] = B;
    __syncthreads();
    for (int off = 1; off < 256; off <<= 1) {
        float pA = 1.f, pB = 0.f;
        if (tid >= off) { pA = sA[tid - off]; pB = sB[tid - off]; }
        __syncthreads();
        if (tid >= off) {
            float cA = sA[tid], cB = sB[tid];
            sA[tid] = pA * cA;
            sB[tid] = fmaf(cA, pB, cB);
        }
        __syncthreads();
    }
    float eB = (tid > 0) ? sB[tid - 1] : 0.f;
    for (int j = 0; j < per; ++j) {
        int p = tid * per + j;
        int c = fwd ? p : (nch - 1 - p);
        hinit[(size_t)c * D + n] = eB;
        eB = fmaf(lA[j], eB, lB[j]);
    }
    if (out_final != nullptr && tid == 0) out_final[n] = sB[255];
}

// ---------------------------------------------------------------------------
extern "C" void kernel_launch(void* const* d_in, const int* in_sizes, int n_in,
                              void* d_out, int out_size, void* d_ws, size_t ws_size,
                              hipStream_t stream) {
    const float* story    = (const float*)d_in[0];
    const float* question = (const float*)d_in[1];
    const float* Wz_f = (const float*)d_in[2];
    const float* bz_f = (const float*)d_in[3];
    const float* Wh_f = (const float*)d_in[4];
    const float* bh_f = (const float*)d_in[5];
    const float* Wz_b = (const float*)d_in[6];
    const float* bz_b = (const float*)d_in[7];
    const float* Wh_b = (const float*)d_in[8];
    const float* bh_b = (const float*)d_in[9];

    const int T    = in_sizes[0] / D;            // 65536
    const int NCH  = T / BT;                     // 512
    const size_t TD = (size_t)T * D;
    const size_t WTE = 5 * 3 * 65536;

    // Tier A needs xb + qA + qB + xq (bf16) + wt + agg
    const size_t needA = 4 * TD * 2 + WTE * 2 + (size_t)NCH * D * 4 * 2 + 4096;
    const bool bigws = ws_size >= needA;

    u16 *xb = nullptr, *qA, *qB, *xq = nullptr, *wt;
    float *aggA, *aggB, *hini;
    if (bigws) {
        xb = (u16*)d_ws;
        qA = xb + TD; qB = qA + TD; xq = qB + TD; wt = xq + TD;
    } else {
        qA = (u16*)d_ws; qB = qA + TD; wt = qB + TD;
    }
    aggA = (float*)(wt + WTE);
    aggB = aggA + (size_t)NCH * D;
    hini = aggB;                                 // alias (safe, see scan_p2)

    wtrans_kernel<<<dim3(5 * 3 * 65536 / 256), dim3(256), 0, stream>>>(
        Wz_f, Wh_f, Wz_b, Wh_b, wt);
    if (bigws) {
        prep0_kernel<<<dim3((unsigned)(TD / 8 / 256)), dim3(256), 0, stream>>>(
            story, question, xb, qA, xq);
    } else {
        q_init_kernel<<<dim3((unsigned)(TD / 8 / 256)), dim3(256), 0, stream>>>(
            qA, question, (long)(TD / 8));
    }

    const u16* qcur  = qA;
    u16*       qnext = qB;
    dim3 gGrid((unsigned)(NCH * 4));             // 2048 blocks
    dim3 blk(256);

    for (int l = 0; l < 3; ++l) {
        const u16*   wtf = wt + (size_t)l * 3 * 65536;
        const float* bzf = bz_f + (size_t)l * D;
        const float* bhf = bh_f + (size_t)l * D;

        if (l == 2) {
            if (bigws)
                qrn_gemm<1,0,1><<<gGrid, blk, 0, stream>>>(nullptr, xb, qcur, xq,
                    wtf, bzf, bhf, aggA, aggB, nullptr, nullptr);
            else
                qrn_gemm<1,0,0><<<gGrid, blk, 0, stream>>>(story, nullptr, qcur, nullptr,
                    wtf, bzf, bhf, aggA, aggB, nullptr, nullptr);
            scan_p2_kernel<<<dim3(D), blk, 0, stream>>>(
                aggA, aggB, hini, (float*)d_out, 1, NCH);
            break;
        }

        const u16*   wtb = wt + (size_t)(3 + l) * 3 * 65536;
        const float* bzb = bz_b + (size_t)l * D;
        const float* bhb = bh_b + (size_t)l * D;

        if (bigws) {
            qrn_gemm<1,0,1><<<gGrid, blk, 0, stream>>>(nullptr, xb, qcur, xq,
                wtf, bzf, bhf, aggA, aggB, nullptr, nullptr);
            scan_p2_kernel<<<dim3(D), blk, 0, stream>>>(aggA, aggB, hini, nullptr, 1, NCH);
            qrn_gemm<1,1,1><<<gGrid, blk, 0, stream>>>(nullptr, xb, qcur, xq,
                wtf, bzf, bhf, nullptr, nullptr, hini, qnext);

            qrn_gemm<0,0,1><<<gGrid, blk, 0, stream>>>(nullptr, xb, qcur, xq,
                wtb, bzb, bhb, aggA, aggB, nullptr, nullptr);
            scan_p2_kernel<<<dim3(D), blk, 0, stream>>>(aggA, aggB, hini, nullptr, 0, NCH);
            qrn_gemm<0,1,1><<<gGrid, blk, 0, stream>>>(nullptr, xb, qcur, xq,
                wtb, bzb, bhb, nullptr, nullptr, hini, qnext);

            xq_upd_kernel<<<dim3((unsigned)(TD / 8 / 256)), blk, 0, stream>>>(xb, qnext, xq);
        } else {
            qrn_gemm<1,0,0><<<gGrid, blk, 0, stream>>>(story, nullptr, qcur, nullptr,
                wtf, bzf, bhf, aggA, aggB, nullptr, nullptr);
            scan_p2_kernel<<<dim3(D), blk, 0, stream>>>(aggA, aggB, hini, nullptr, 1, NCH);
            qrn_gemm<1,1,0><<<gGrid, blk, 0, stream>>>(story, nullptr, qcur, nullptr,
                wtf, bzf, bhf, nullptr, nullptr, hini, qnext);

            qrn_gemm<0,0,0><<<gGrid, blk, 0, stream>>>(story, nullptr, qcur, nullptr,
                wtb, bzb, bhb, aggA, aggB, nullptr, nullptr);
            scan_p2_kernel<<<dim3(D), blk, 0, stream>>>(aggA, aggB, hini, nullptr, 0, NCH);
            qrn_gemm<0,1,0><<<gGrid, blk, 0, stream>>>(story, nullptr, qcur, nullptr,
                wtb, bzb, bhb, nullptr, nullptr, hini, qnext);
        }

        const u16* tswap = qcur; qcur = qnext; qnext = (u16*)tswap;
    }
}